// Round 1
// baseline (157.069 us; speedup 1.0000x reference)
//
#include <hip/hip_runtime.h>
#include <hip/hip_bf16.h>

#define IN_C  128
#define HID_C 64
#define OUT_C 32
#define NEG_SLOPE 0.2f
#define EPB1    2048     // edges per bin1 block
#define EPB2    2048     // records per bin2 part
#define BUCKETW 64       // dst nodes per region
#define RCAP    1536     // region capacity (mean 1023, +16 sigma)
#define SUPW    1024     // dst nodes per super-bucket
#define RCAP1   18432    // super capacity (mean 16327)
#define PARTS   9        // bin2 parts per super
#define CSTRIDE 16       // cursor padding (64B) to spread atomic lines
#define XS_LD   136      // LDS tile leading dim (ushorts): 272B rows, 16B-aligned

typedef short bf16x8 __attribute__((ext_vector_type(8)));
typedef float f32x4  __attribute__((ext_vector_type(4)));

__device__ __forceinline__ unsigned short f2bf(float f) {
    __hip_bfloat16 h = __float2bfloat16(f);
    return *(unsigned short*)&h;
}
__device__ __forceinline__ float bflo(unsigned int u) {
    return __uint_as_float(u << 16);
}
__device__ __forceinline__ float bfhi(unsigned int u) {
    return __uint_as_float(u & 0xffff0000u);
}

// ---------------------------------------------------------------------------
// Kernel 1 (FUSED): blocks [0, ngemm) = 64-node gemm+logits tile;
// blocks [ngemm, ngemm+nbin) = bin1 edge-binning (pure int, unchanged).
// gemm path R19: 64 rows/block, W staged transposed in LDS (vector loads,
// ds_read_b128 frags), wave-private row tiles, in-wave logits reduction,
// single barrier.
// ---------------------------------------------------------------------------
__global__ __launch_bounds__(256) void gemm_bin1_kernel(
    const float* __restrict__ x, const float* __restrict__ W,
    const float* __restrict__ att_src, const float* __restrict__ att_dst,
    __hip_bfloat16* __restrict__ hb,
    float* __restrict__ a_src, float* __restrict__ a_dst,
    const int* __restrict__ ei, int E,
    int* __restrict__ bcur1, unsigned* __restrict__ superbuf,
    int ngemm, int n_nodes)
{
    __shared__ __align__(16) unsigned char smem[34816];
    const int t = threadIdx.x;

    if ((int)blockIdx.x < ngemm) {
        // ---------------- gemm path ----------------
        unsigned short* xs = (unsigned short*)smem;            // 64*136*2 = 17408 B
        unsigned short* wt = (unsigned short*)(smem + 17408);  // 64*136*2 = 17408 B
        const int wv   = t >> 6;
        const int lane = t & 63;
        const int m16  = lane & 15;
        const int quad = lane >> 4;
        const int node0 = blockIdx.x * 64;
        const int nrows = min(64, n_nodes - node0);

        // stage x tile: 64x128 f32 -> bf16 LDS (coalesced float4)
        {
            const float4* xg = (const float4*)(x + (long)node0 * IN_C);
#pragma unroll
            for (int i = t; i < 2048; i += 256) {
                const int row = i >> 5;
                const int c4  = i & 31;
                float4 v = (row < nrows) ? xg[i] : make_float4(0.f, 0.f, 0.f, 0.f);
                ushort4 u;
                u.x = f2bf(v.x); u.y = f2bf(v.y);
                u.z = f2bf(v.z); u.w = f2bf(v.w);
                *(ushort4*)(xs + row * XS_LD + c4 * 4) = u;
            }
        }
        // stage W transposed: Wt[n][k] bf16 (coalesced float4 reads of W[k][n])
        {
#pragma unroll
            for (int i = t; i < 2048; i += 256) {
                const int k  = i >> 4;
                const int n0 = (i & 15) * 4;
                const float4 v = *(const float4*)(W + k * HID_C + n0);
                wt[(n0 + 0) * XS_LD + k] = f2bf(v.x);
                wt[(n0 + 1) * XS_LD + k] = f2bf(v.y);
                wt[(n0 + 2) * XS_LD + k] = f2bf(v.z);
                wt[(n0 + 3) * XS_LD + k] = f2bf(v.w);
            }
        }
        __syncthreads();

        // wave-private 16-row tile: rows [wv*16, wv*16+16)
        const int myrow0 = wv * 16;
        bf16x8 A[4];
#pragma unroll
        for (int k0 = 0; k0 < 4; ++k0)
            A[k0] = *(const bf16x8*)(xs + (myrow0 + m16) * XS_LD + k0 * 32 + quad * 8);

        f32x4 C[4];
#pragma unroll
        for (int c = 0; c < 4; ++c) {
            C[c] = (f32x4){0.f, 0.f, 0.f, 0.f};
#pragma unroll
            for (int k0 = 0; k0 < 4; ++k0) {
                const bf16x8 B = *(const bf16x8*)(wt + (c * 16 + m16) * XS_LD + k0 * 32 + quad * 8);
                C[c] = __builtin_amdgcn_mfma_f32_16x16x32_bf16(A[k0], B, C[c], 0, 0, 0);
            }
        }

        // store h (bf16): row = myrow0 + quad*4 + r, col = c*16 + m16
#pragma unroll
        for (int c = 0; c < 4; ++c) {
#pragma unroll
            for (int r = 0; r < 4; ++r) {
                const int row = myrow0 + quad * 4 + r;
                if (row < nrows)
                    hb[(long)(node0 + row) * HID_C + c * 16 + m16] = __float2bfloat16(C[c][r]);
            }
        }

        // logits: fully in-wave reduction (no LDS, no second barrier)
        {
            float ps[4] = {0.f, 0.f, 0.f, 0.f};
            float pd[4] = {0.f, 0.f, 0.f, 0.f};
#pragma unroll
            for (int c = 0; c < 4; ++c) {
                const float av = att_src[c * 16 + m16];
                const float dv = att_dst[c * 16 + m16];
#pragma unroll
                for (int r = 0; r < 4; ++r) {
                    ps[r] = fmaf(C[c][r], av, ps[r]);
                    pd[r] = fmaf(C[c][r], dv, pd[r]);
                }
            }
#pragma unroll
            for (int off = 1; off <= 8; off <<= 1) {
#pragma unroll
                for (int r = 0; r < 4; ++r) {
                    ps[r] += __shfl_xor(ps[r], off, 64);
                    pd[r] += __shfl_xor(pd[r], off, 64);
                }
            }
            if (m16 == 0) {
#pragma unroll
                for (int r = 0; r < 4; ++r) {
                    const int row = myrow0 + quad * 4 + r;
                    if (row < nrows) {
                        a_src[node0 + row] = ps[r];
                        a_dst[node0 + row] = pd[r];
                    }
                }
            }
        }
    } else {
        // ---------------- bin1 path (pure int, unchanged) ----------------
        unsigned* stage = (unsigned*)smem;                   // 8192 B
        int* excl = (int*)(smem + 8192);
        int* cur  = (int*)(smem + 8448);
        int* gpos = (int*)(smem + 8704);

        const int base = (blockIdx.x - ngemm) * EPB1;
        const int nedge = min(EPB1, E - base);

        if (t < 64) excl[t] = 0;
        __syncthreads();

        for (int i = t; i < nedge; i += 256)
            atomicAdd(&excl[ei[E + base + i] >> 10], 1);
        __syncthreads();

        if (t < 64) {
            int c = excl[t], incl = c;
#pragma unroll
            for (int off = 1; off <= 32; off <<= 1) {
                int u = __shfl_up(incl, off, 64);
                if (t >= off) incl += u;
            }
            excl[t] = incl - c;
            cur[t]  = incl - c;
        }
        __syncthreads();

        for (int i = t; i < nedge; i += 256) {
            const int s = ei[base + i];
            const int d = ei[E + base + i];
            const int sq = d >> 10;
            const int pos = atomicAdd(&cur[sq], 1);
            stage[pos] = (unsigned)s | ((unsigned)(d & 1023) << 16)
                         | ((unsigned)sq << 26);
        }
        __syncthreads();

        if (t < 64) {
            const int c = cur[t] - excl[t];
            gpos[t] = (c > 0) ? atomicAdd(&bcur1[t * CSTRIDE], c) : 0;
        }
        __syncthreads();

        for (int i = t; i < nedge; i += 256) {
            const unsigned r = stage[i];
            const int sq = r >> 26;
            const int dp = gpos[sq] + (i - excl[sq]);
            if (dp < RCAP1) superbuf[(long)sq * RCAP1 + dp] = r;
        }
    }
}

// ---------------------------------------------------------------------------
// Kernel 2 (bin level 2, unchanged): super-buckets -> 64-dst regions.
// ---------------------------------------------------------------------------
__global__ __launch_bounds__(256) void bin2_kernel(
    const unsigned* __restrict__ superbuf, const int* __restrict__ bcur1,
    int* __restrict__ bcur2, unsigned* __restrict__ bucketbuf)
{
    __shared__ unsigned srt[EPB2];   // 8 KB
    __shared__ int cnt[16];
    __shared__ int rp[16];
    __shared__ int cur16[16];
    __shared__ int gpos[16];

    const int t    = threadIdx.x;
    const int sq   = blockIdx.x / PARTS;
    const int part = blockIdx.x % PARTS;
    const int tot  = min(bcur1[sq * CSTRIDE], RCAP1);
    const int beg  = part * EPB2;
    const int n    = min(EPB2, tot - beg);
    if (n <= 0) return;                       // block-uniform

    if (t < 16) cnt[t] = 0;
    __syncthreads();

    const unsigned* src = superbuf + (long)sq * RCAP1 + beg;

    for (int i = t; i < n; i += 256)
        atomicAdd(&cnt[(src[i] >> 22) & 15], 1);
    __syncthreads();

    if (t == 0) {
        int run = 0;
#pragma unroll
        for (int k = 0; k < 16; ++k) { rp[k] = run; cur16[k] = run; run += cnt[k]; }
    }
    __syncthreads();

    for (int i = t; i < n; i += 256) {
        const unsigned r = src[i];
        const int pos = atomicAdd(&cur16[(r >> 22) & 15], 1);
        srt[pos] = r;
    }
    __syncthreads();

    if (t < 16) {
        const int c = cnt[t];
        const int q2 = sq * 16 + t;
        gpos[t] = (c > 0) ? atomicAdd(&bcur2[q2 * CSTRIDE], c) : 0;
    }
    __syncthreads();

    for (int i = t; i < n; i += 256) {
        const unsigned r = srt[i];
        const int idx = (r >> 22) & 15;
        const int dp  = gpos[idx] + (i - rp[idx]);
        const int q2  = sq * 16 + idx;
        const unsigned nx = (r & 0xFFFFu) | (((r >> 16) & 63u) << 16);
        if (dp < RCAP) bucketbuf[(long)q2 * RCAP + dp] = nx;
    }
}

// ---------------------------------------------------------------------------
// Kernel 3 (R19): per-region aggregation, TWO dlocs in flight per wave
// (pairs wv+16p / wv+16p+8) to double gather MLP and halve the serial
// latency rounds. Per-dloc accumulation order identical to R18.
// ---------------------------------------------------------------------------
__global__ __launch_bounds__(512) void bucket_agg_kernel(
    const unsigned* __restrict__ bucketbuf, const int* __restrict__ bcursor,
    const __hip_bfloat16* __restrict__ hb,
    const float* __restrict__ a_src, const float* __restrict__ a_dst,
    const float* __restrict__ bias_conv,
    const float* __restrict__ W_lin, const float* __restrict__ b_lin,
    float* __restrict__ out, int n_nodes)
{
    __shared__ unsigned srtL[RCAP];     // 6 KB
    __shared__ int cntd[BUCKETW];
    __shared__ int rp[BUCKETW + 1];
    __shared__ int curd[BUCKETW];

    const int t  = threadIdx.x;
    const int q  = blockIdx.x;
    const int d0 = q * BUCKETW;
    const int dmax = min(BUCKETW, n_nodes - d0);
    const int tot  = min(bcursor[q * CSTRIDE], RCAP);
    const int wv = t >> 6, lane = t & 63, g8 = lane >> 3, l = lane & 7;

    if (t < BUCKETW) cntd[t] = 0;
    __syncthreads();

    const unsigned* gsrc = bucketbuf + (long)q * RCAP;

    // pass 1: count per dloc
    for (int i = t; i < tot; i += 512)
        atomicAdd(&cntd[(gsrc[i] >> 16) & 63], 1);
    __syncthreads();

    // one-wave scan of 64 counters
    if (t < 64) {
        int c = cntd[t], incl = c;
#pragma unroll
        for (int off = 1; off <= 32; off <<= 1) {
            int u = __shfl_up(incl, off, 64);
            if (t >= off) incl += u;
        }
        rp[t] = incl - c;
        curd[t] = incl - c;
        if (t == 63) rp[64] = incl;
    }
    __syncthreads();

    // pass 2: scatter into sorted LDS order (second read is L2-hot)
    for (int i = t; i < tot; i += 512) {
        const unsigned r = gsrc[i];
        const int pos = atomicAdd(&curd[(r >> 16) & 63], 1);
        srtL[pos] = r;
    }
    __syncthreads();

    // per-lane epilogue constants
    float Wr[8][4];
#pragma unroll
    for (int kc = 0; kc < 8; ++kc)
#pragma unroll
        for (int kj = 0; kj < 4; ++kj)
            Wr[kc][kj] = W_lin[(l * 8 + kc) * OUT_C + g8 * 4 + kj];
    float biasR[8];
#pragma unroll
    for (int kc = 0; kc < 8; ++kc) biasR[kc] = bias_conv[l * 8 + kc];
    float blinR[4];
#pragma unroll
    for (int kj = 0; kj < 4; ++kj) blinR[kj] = b_lin[g8 * 4 + kj];

    const unsigned short* hbs = (const unsigned short*)hb;

    for (int p = 0; p < 4; ++p) {
        const int dA = wv + p * 16;
        if (dA >= dmax) break;
        const int dB = dA + 8;
        const bool vB = dB < dmax;
        const int gA = d0 + dA;
        const int gB = d0 + (vB ? dB : dA);       // always a valid address
        const float adA = a_dst[gA];
        const float adB = a_dst[gB];
        float Aa[8] = {0.f,0.f,0.f,0.f,0.f,0.f,0.f,0.f};
        float Ab[8] = {0.f,0.f,0.f,0.f,0.f,0.f,0.f,0.f};
        float denA = 0.f, denB = 0.f;

        if (g8 == 0) {        // self-loops on slot 0
            {
                float e = a_src[gA] + adA;
                e = (e >= 0.f) ? e : NEG_SLOPE * e;
                const float ws = __expf(e);
                const uint4 hv = *(const uint4*)(hbs + (long)gA * HID_C + l * 8);
                denA = ws;
                Aa[0] = ws * bflo(hv.x); Aa[1] = ws * bfhi(hv.x);
                Aa[2] = ws * bflo(hv.y); Aa[3] = ws * bfhi(hv.y);
                Aa[4] = ws * bflo(hv.z); Aa[5] = ws * bfhi(hv.z);
                Aa[6] = ws * bflo(hv.w); Aa[7] = ws * bfhi(hv.w);
            }
            if (vB) {
                float e = a_src[gB] + adB;
                e = (e >= 0.f) ? e : NEG_SLOPE * e;
                const float ws = __expf(e);
                const uint4 hv = *(const uint4*)(hbs + (long)gB * HID_C + l * 8);
                denB = ws;
                Ab[0] = ws * bflo(hv.x); Ab[1] = ws * bfhi(hv.x);
                Ab[2] = ws * bflo(hv.y); Ab[3] = ws * bfhi(hv.y);
                Ab[4] = ws * bflo(hv.z); Ab[5] = ws * bfhi(hv.z);
                Ab[6] = ws * bflo(hv.w); Ab[7] = ws * bfhi(hv.w);
            }
        }

        const int begA = rp[dA],            finA = rp[dA + 1];
        const int begB = vB ? rp[dB] : 0;
        const int finB = vB ? rp[dB + 1] : 0;
        int jA = begA + g8, jB = begB + g8;

        while ((jA < finA) | (jB < finB)) {
            // loop only runs if tot > 0, so srtL[0] is a valid record (fallback)
            const bool hA0 = jA < finA,       hA1 = (jA + 8) < finA;
            const bool hB0 = jB < finB,       hB1 = (jB + 8) < finB;
            const unsigned rA0 = srtL[hA0 ? jA       : 0];
            const unsigned rA1 = srtL[hA1 ? (jA + 8) : 0];
            const unsigned rB0 = srtL[hB0 ? jB       : 0];
            const unsigned rB1 = srtL[hB1 ? (jB + 8) : 0];
            const int sA0 = rA0 & 0xFFFF, sA1 = rA1 & 0xFFFF;
            const int sB0 = rB0 & 0xFFFF, sB1 = rB1 & 0xFFFF;
            const float xA0 = a_src[sA0];
            const float xA1 = a_src[sA1];
            const float xB0 = a_src[sB0];
            const float xB1 = a_src[sB1];
            const uint4 hA0v = *(const uint4*)(hbs + (long)sA0 * HID_C + l * 8);
            const uint4 hA1v = *(const uint4*)(hbs + (long)sA1 * HID_C + l * 8);
            const uint4 hB0v = *(const uint4*)(hbs + (long)sB0 * HID_C + l * 8);
            const uint4 hB1v = *(const uint4*)(hbs + (long)sB1 * HID_C + l * 8);
            float e0 = xA0 + adA; e0 = (e0 >= 0.f) ? e0 : NEG_SLOPE * e0;
            float e1 = xA1 + adA; e1 = (e1 >= 0.f) ? e1 : NEG_SLOPE * e1;
            float e2 = xB0 + adB; e2 = (e2 >= 0.f) ? e2 : NEG_SLOPE * e2;
            float e3 = xB1 + adB; e3 = (e3 >= 0.f) ? e3 : NEG_SLOPE * e3;
            const float wA0 = hA0 ? __expf(e0) : 0.f;
            const float wA1 = hA1 ? __expf(e1) : 0.f;
            const float wB0 = hB0 ? __expf(e2) : 0.f;
            const float wB1 = hB1 ? __expf(e3) : 0.f;
            denA += wA0 + wA1;
            denB += wB0 + wB1;
            Aa[0] = fmaf(wA0, bflo(hA0v.x), Aa[0]); Aa[1] = fmaf(wA0, bfhi(hA0v.x), Aa[1]);
            Aa[2] = fmaf(wA0, bflo(hA0v.y), Aa[2]); Aa[3] = fmaf(wA0, bfhi(hA0v.y), Aa[3]);
            Aa[4] = fmaf(wA0, bflo(hA0v.z), Aa[4]); Aa[5] = fmaf(wA0, bfhi(hA0v.z), Aa[5]);
            Aa[6] = fmaf(wA0, bflo(hA0v.w), Aa[6]); Aa[7] = fmaf(wA0, bfhi(hA0v.w), Aa[7]);
            Aa[0] = fmaf(wA1, bflo(hA1v.x), Aa[0]); Aa[1] = fmaf(wA1, bfhi(hA1v.x), Aa[1]);
            Aa[2] = fmaf(wA1, bflo(hA1v.y), Aa[2]); Aa[3] = fmaf(wA1, bfhi(hA1v.y), Aa[3]);
            Aa[4] = fmaf(wA1, bflo(hA1v.z), Aa[4]); Aa[5] = fmaf(wA1, bfhi(hA1v.z), Aa[5]);
            Aa[6] = fmaf(wA1, bflo(hA1v.w), Aa[6]); Aa[7] = fmaf(wA1, bfhi(hA1v.w), Aa[7]);
            Ab[0] = fmaf(wB0, bflo(hB0v.x), Ab[0]); Ab[1] = fmaf(wB0, bfhi(hB0v.x), Ab[1]);
            Ab[2] = fmaf(wB0, bflo(hB0v.y), Ab[2]); Ab[3] = fmaf(wB0, bfhi(hB0v.y), Ab[3]);
            Ab[4] = fmaf(wB0, bflo(hB0v.z), Ab[4]); Ab[5] = fmaf(wB0, bfhi(hB0v.z), Ab[5]);
            Ab[6] = fmaf(wB0, bflo(hB0v.w), Ab[6]); Ab[7] = fmaf(wB0, bfhi(hB0v.w), Ab[7]);
            Ab[0] = fmaf(wB1, bflo(hB1v.x), Ab[0]); Ab[1] = fmaf(wB1, bfhi(hB1v.x), Ab[1]);
            Ab[2] = fmaf(wB1, bflo(hB1v.y), Ab[2]); Ab[3] = fmaf(wB1, bfhi(hB1v.y), Ab[3]);
            Ab[4] = fmaf(wB1, bflo(hB1v.z), Ab[4]); Ab[5] = fmaf(wB1, bfhi(hB1v.z), Ab[5]);
            Ab[6] = fmaf(wB1, bflo(hB1v.w), Ab[6]); Ab[7] = fmaf(wB1, bfhi(hB1v.w), Ab[7]);
            jA += 16; jB += 16;
        }

        // ---- reduce + epilogue: A ----
#pragma unroll
        for (int off = 8; off <= 32; off <<= 1) {
#pragma unroll
            for (int k = 0; k < 8; ++k) Aa[k] += __shfl_xor(Aa[k], off, 64);
            denA += __shfl_xor(denA, off, 64);
        }
        {
            const float rd = 1.0f / (denA + 1e-16f);
            float p0 = 0.f, p1 = 0.f, p2 = 0.f, p3 = 0.f;
#pragma unroll
            for (int kc = 0; kc < 8; ++kc) {
                float vv = fmaf(Aa[kc], rd, biasR[kc]);
                vv = vv > 0.f ? vv : 0.f;
                p0 = fmaf(vv, Wr[kc][0], p0);
                p1 = fmaf(vv, Wr[kc][1], p1);
                p2 = fmaf(vv, Wr[kc][2], p2);
                p3 = fmaf(vv, Wr[kc][3], p3);
            }
#pragma unroll
            for (int off = 1; off <= 4; off <<= 1) {
                p0 += __shfl_xor(p0, off, 64);
                p1 += __shfl_xor(p1, off, 64);
                p2 += __shfl_xor(p2, off, 64);
                p3 += __shfl_xor(p3, off, 64);
            }
            if (l == 0) {
                float4 o = make_float4(p0 + blinR[0], p1 + blinR[1],
                                       p2 + blinR[2], p3 + blinR[3]);
                *(float4*)(out + (long)gA * OUT_C + g8 * 4) = o;
            }
        }
        // ---- reduce + epilogue: B ----
#pragma unroll
        for (int off = 8; off <= 32; off <<= 1) {
#pragma unroll
            for (int k = 0; k < 8; ++k) Ab[k] += __shfl_xor(Ab[k], off, 64);
            denB += __shfl_xor(denB, off, 64);
        }
        {
            const float rd = 1.0f / (denB + 1e-16f);
            float p0 = 0.f, p1 = 0.f, p2 = 0.f, p3 = 0.f;
#pragma unroll
            for (int kc = 0; kc < 8; ++kc) {
                float vv = fmaf(Ab[kc], rd, biasR[kc]);
                vv = vv > 0.f ? vv : 0.f;
                p0 = fmaf(vv, Wr[kc][0], p0);
                p1 = fmaf(vv, Wr[kc][1], p1);
                p2 = fmaf(vv, Wr[kc][2], p2);
                p3 = fmaf(vv, Wr[kc][3], p3);
            }
#pragma unroll
            for (int off = 1; off <= 4; off <<= 1) {
                p0 += __shfl_xor(p0, off, 64);
                p1 += __shfl_xor(p1, off, 64);
                p2 += __shfl_xor(p2, off, 64);
                p3 += __shfl_xor(p3, off, 64);
            }
            if (l == 0 && vB) {
                float4 o = make_float4(p0 + blinR[0], p1 + blinR[1],
                                       p2 + blinR[2], p3 + blinR[3]);
                *(float4*)(out + (long)(d0 + dB) * OUT_C + g8 * 4) = o;
            }
        }
    }
}

// ---------------------------------------------------------------------------
extern "C" void kernel_launch(void* const* d_in, const int* in_sizes, int n_in,
                              void* d_out, int out_size, void* d_ws, size_t ws_size,
                              hipStream_t stream) {
    const float* x         = (const float*)d_in[0];
    const int*   ei        = (const int*)d_in[1];
    const float* W         = (const float*)d_in[2];
    const float* att_src   = (const float*)d_in[3];
    const float* att_dst   = (const float*)d_in[4];
    const float* bias_conv = (const float*)d_in[5];
    const float* W_lin     = (const float*)d_in[6];
    const float* b_lin     = (const float*)d_in[7];
    float*       out       = (float*)d_out;

    const int n_nodes = in_sizes[0] / IN_C;              // 50000
    const int E       = in_sizes[1] / 2;                 // 800000
    const int B1   = (E + EPB1 - 1) / EPB1;              // 391 bin1 blocks
    const int Q    = (n_nodes + BUCKETW - 1) / BUCKETW;  // 782 regions
    const int NSUP = (n_nodes + SUPW - 1) / SUPW;        // 49 supers
    const int NG   = (n_nodes + 63) / 64;                // 782 gemm blocks (64 rows)

    // workspace layout (bcur1 ++ bcur2 contiguous -> one memset)
    __hip_bfloat16* hb = (__hip_bfloat16*)d_ws;              // N*64 bf16 (6.4MB)
    float* a_src   = (float*)(hb + (long)n_nodes * HID_C);   // N f
    float* a_dst   = a_src + n_nodes;                        // N f
    int*   bcur1   = (int*)(a_dst + n_nodes);                // NSUP*CSTRIDE
    int*   bcur2   = bcur1 + NSUP * CSTRIDE;                 // Q*CSTRIDE
    unsigned* superbuf  = (unsigned*)(bcur2 + (long)Q * CSTRIDE); // 3.6MB
    unsigned* bucketbuf = superbuf + (long)NSUP * RCAP1;          // 4.8MB

    // 0) zero both cursor arrays in one stream-ordered memset
    hipMemsetAsync(bcur1, 0,
                   (size_t)(NSUP + Q) * CSTRIDE * sizeof(int), stream);

    // 1) FUSED: gemm+logits (blocks 0..NG-1)  ||  bin1 (blocks NG..NG+B1-1)
    gemm_bin1_kernel<<<NG + B1, 256, 0, stream>>>(
        x, W, att_src, att_dst, hb, a_src, a_dst,
        ei, E, bcur1, superbuf, NG, n_nodes);

    // 2) bin level 2: super-buckets -> regions
    bin2_kernel<<<NSUP * PARTS, 256, 0, stream>>>(
        superbuf, bcur1, bcur2, bucketbuf);

    // 3) per-region aggregation, 2 dlocs in flight per wave
    bucket_agg_kernel<<<Q, 512, 0, stream>>>(
        bucketbuf, bcur2, hb, a_src, a_dst,
        bias_conv, W_lin, b_lin, out, n_nodes);
}